// Round 3
// baseline (1467.594 us; speedup 1.0000x reference)
//
#include <hip/hip_runtime.h>
#include <hip/hip_bf16.h>

#define NN 100000     // nodes
#define NE 1000000    // edges
#define HD 64         // feature dim (F_IN == H == 64)
#define NB 128        // graphs
#define NC 10         // classes
#define NEG_SLOPE 0.01f
#define INV_TEMP 20.0f   // 1/0.05

// ---- pass 1 over edges: in-degree histogram, weighted degree, per-node max(ew) ----
__global__ void k_edge1(const int* __restrict__ ei, const float* __restrict__ ew,
                        int* __restrict__ cnt, float* __restrict__ degf,
                        unsigned int* __restrict__ mmax) {
    int e = blockIdx.x * 256 + threadIdx.x;
    if (e >= NE) return;
    int r = ei[e], c = ei[NE + e];
    float w = ew[e];
    atomicAdd(&cnt[c], 1);
    atomicAdd(&degf[c], w);
    unsigned int wb = __float_as_uint(w);   // ew >= 0 -> uint order == float order
    atomicMax(&mmax[r], wb);
    atomicMax(&mmax[c], wb);
}

// ---- dis = rsqrt(deg), deg includes self-loop weight 1 ----
__global__ void k_node1(const float* __restrict__ degf, float* __restrict__ dis) {
    int i = blockIdx.x * 256 + threadIdx.x;
    if (i < NN) dis[i] = rsqrtf(degf[i] + 1.0f);
}

// ---- single-block exclusive scan of cnt -> indptr, cursor ----
__global__ void k_scan(const int* __restrict__ cnt, int* __restrict__ indptr,
                       int* __restrict__ cursor) {
    __shared__ int sums[1024];
    const int t = threadIdx.x;
    const int PER = (NN + 1023) / 1024;   // 98
    int i0 = t * PER, i1 = min(NN, i0 + PER);
    int s = 0;
    for (int i = i0; i < i1; ++i) s += cnt[i];
    sums[t] = s;
    __syncthreads();
    for (int d = 1; d < 1024; d <<= 1) {
        int v = (t >= d) ? sums[t - d] : 0;
        __syncthreads();
        sums[t] += v;
        __syncthreads();
    }
    int pref = (t == 0) ? 0 : sums[t - 1];
    for (int i = i0; i < i1; ++i) {
        indptr[i] = pref; cursor[i] = pref;
        pref += cnt[i];
    }
    if (t == 0) indptr[NN] = NE;
}

// ---- pass 2 over edges: norm + CSR scatter + smooth-max softmax accumulation ----
__global__ void k_edge2(const int* __restrict__ ei, const float* __restrict__ ew,
                        const float* __restrict__ dis, const float* __restrict__ m,
                        int* __restrict__ cursor, int* __restrict__ srt_row,
                        float* __restrict__ srt_norm,
                        float* __restrict__ den, float* __restrict__ num) {
    int e = blockIdx.x * 256 + threadIdx.x;
    if (e >= NE) return;
    int r = ei[e], c = ei[NE + e];
    float w = ew[e];
    float nrm = dis[r] * w * dis[c];
    int p = atomicAdd(&cursor[c], 1);
    srt_row[p] = r;
    srt_norm[p] = nrm;
    float ar = __expf((w - m[r]) * INV_TEMP);
    atomicAdd(&den[r], ar);
    atomicAdd(&num[r], w * ar);
    float ac = __expf((w - m[c]) * INV_TEMP);
    atomicAdd(&den[c], ac);
    atomicAdd(&num[c], w * ac);
}

// ---- nw = num/den (0 for isolated) ----
__global__ void k_node2(const float* __restrict__ den, const float* __restrict__ num,
                        float* __restrict__ nw) {
    int i = blockIdx.x * 256 + threadIdx.x;
    if (i < NN) {
        float d = den[i];
        nw[i] = (d > 0.f) ? num[i] / fmaxf(d, 1e-16f) : 0.f;
    }
}

// ---- dense GEMM: T[N,64] = Hin[N,64] @ W[64,64]; 16 rows/block ----
__global__ void k_gemm(const float* __restrict__ Hin, const float* __restrict__ W,
                       float* __restrict__ T) {
    __shared__ float Ws[64 * 64];
    __shared__ float Hs[16 * 64];
    int tid = threadIdx.x;
    for (int i = tid; i < 64 * 64; i += 256) Ws[i] = W[i];
    int row0 = blockIdx.x * 16;   // NN % 16 == 0 -> no guard
    for (int i = tid; i < 16 * 64; i += 256)
        Hs[i] = Hin[(row0 + (i >> 6)) * HD + (i & 63)];
    __syncthreads();
    int j = tid & 63, rq = tid >> 6;
    float acc[4] = {0.f, 0.f, 0.f, 0.f};
    for (int k = 0; k < 64; ++k) {
        float wv = Ws[k * 64 + j];
#pragma unroll
        for (int rr = 0; rr < 4; ++rr)
            acc[rr] += Hs[(rq * 4 + rr) * 64 + k] * wv;
    }
#pragma unroll
    for (int rr = 0; rr < 4; ++rr)
        T[(row0 + rq * 4 + rr) * HD + j] = acc[rr];
}

// ---- CSR aggregation: one wave per node, lane = feature ----
__global__ void k_agg(const float* __restrict__ T, const int* __restrict__ indptr,
                      const int* __restrict__ srt_row, const float* __restrict__ srt_norm,
                      const float* __restrict__ dis, const float* __restrict__ bias,
                      float* __restrict__ Hout, int lrelu) {
    int wv = threadIdx.x >> 6, lane = threadIdx.x & 63;
    int node = blockIdx.x * 4 + wv;
    if (node >= NN) return;
    float d = dis[node];
    float acc = bias[lane] + d * d * T[node * HD + lane];   // self-loop
    int beg = indptr[node], end = indptr[node + 1];
    for (int e = beg; e < end; ++e) {
        int r = srt_row[e];
        float nm = srt_norm[e];
        acc += nm * T[r * HD + lane];
    }
    if (lrelu) acc = acc > 0.f ? acc : NEG_SLOPE * acc;
    Hout[node * HD + lane] = acc;
}

// ---- graph boundaries from sorted batch ----
__global__ void k_gsinit(int* __restrict__ gstart) {
    int t = threadIdx.x;
    if (t <= NB) gstart[t] = NN;
}
__global__ void k_gsmin(const int* __restrict__ batch, int* __restrict__ gstart) {
    int n = blockIdx.x * 256 + threadIdx.x;
    if (n < NN) atomicMin(&gstart[batch[n]], n);
}
__global__ void k_gsfix(int* __restrict__ gstart) {
    for (int b = NB - 1; b >= 0; --b)
        if (gstart[b] > gstart[b + 1]) gstart[b] = gstart[b + 1];
}

// ---- weighted pooling: one block (4 waves) per graph; fp32 out ----
__global__ void k_pool(const float* __restrict__ H3, const float* __restrict__ nw,
                       const int* __restrict__ gstart, float* __restrict__ sfeat,
                       float* __restrict__ out_feats) {
    __shared__ float sred[4][64];
    __shared__ float wred[4];
    __shared__ float wsum_s;
    int b = blockIdx.x;
    int wv = threadIdx.x >> 6, lane = threadIdx.x & 63;
    int beg = gstart[b], end = gstart[b + 1];
    float accs = 0.f, accw = 0.f;
    for (int n = beg + wv; n < end; n += 4) {
        float wn = nw[n];
        accs += wn * H3[n * HD + lane];
        accw += wn;       // identical across lanes of this wave
    }
    sred[wv][lane] = accs;
    if (lane == 0) wred[wv] = accw;
    __syncthreads();
    if (threadIdx.x < 64) {
        float s = sred[0][lane] + sred[1][lane] + sred[2][lane] + sred[3][lane];
        sred[0][lane] = s;
        if (lane == 0) wsum_s = wred[0] + wred[1] + wred[2] + wred[3];
    }
    __syncthreads();
    if (threadIdx.x < 64) {
        float s = sred[0][lane];
        float mean = s / fmaxf(wsum_s, 1e-16f);
        sfeat[b * 128 + lane] = s;
        sfeat[b * 128 + 64 + lane] = mean;
        out_feats[b * 128 + lane] = s;
        out_feats[b * 128 + 64 + lane] = mean;
    }
}

// ---- head MLP + softmax; one block per graph; fp32 out ----
// out layout (fp32 elements): logits[0,1280) probs[1280,2560) feats[2560,18944)
//                             embeds[18944,27136) hout[27136,35328)
__global__ void k_mlp(const float* __restrict__ sfeat, const float* __restrict__ Wlin,
                      const float* __restrict__ blin, const float* __restrict__ Wout,
                      const float* __restrict__ bout, float* __restrict__ out) {
    __shared__ float fs[128];
    __shared__ float hs[64];
    __shared__ float lg[10];
    int b = blockIdx.x, t = threadIdx.x;   // 128 threads
    fs[t] = sfeat[b * 128 + t];
    __syncthreads();
    if (t < 64) {
        float acc = blin[t];
        for (int k = 0; k < 128; ++k) acc += fs[k] * Wlin[k * 64 + t];
        out[18944 + b * 64 + t] = acc;
        float h = fmaxf(acc, 0.f);
        out[27136 + b * 64 + t] = h;
        hs[t] = h;
    }
    __syncthreads();
    if (t < NC) {
        float acc = bout[t];
        for (int j = 0; j < 64; ++j) acc += hs[j] * Wout[j * NC + t];
        lg[t] = acc;
        out[b * NC + t] = acc;
    }
    __syncthreads();
    if (t < NC) {
        float mx = lg[0];
        for (int k = 1; k < NC; ++k) mx = fmaxf(mx, lg[k]);
        float se = 0.f;
        for (int k = 0; k < NC; ++k) se += __expf(lg[k] - mx);
        float p = __expf(lg[t] - mx) / se;
        out[1280 + b * NC + t] = p;
    }
}

extern "C" void kernel_launch(void* const* d_in, const int* in_sizes, int n_in,
                              void* d_out, int out_size, void* d_ws, size_t ws_size,
                              hipStream_t stream) {
    const float* x    = (const float*)d_in[0];
    const int*   ei   = (const int*)  d_in[1];
    const float* ew   = (const float*)d_in[2];
    const int*   batch= (const int*)  d_in[3];
    const float* W1   = (const float*)d_in[4];
    const float* b1   = (const float*)d_in[5];
    const float* W2   = (const float*)d_in[6];
    const float* b2   = (const float*)d_in[7];
    const float* W3   = (const float*)d_in[8];
    const float* b3   = (const float*)d_in[9];
    const float* Wlin = (const float*)d_in[10];
    const float* blin = (const float*)d_in[11];
    const float* Wout = (const float*)d_in[12];
    const float* bout = (const float*)d_in[13];
    float* out = (float*)d_out;

    char* ws = (char*)d_ws;
    size_t off = 0;
    auto alloc = [&](size_t bytes) -> void* {
        void* p = ws + off;
        off = (off + bytes + 255) & ~(size_t)255;
        return p;
    };
    // zeroed group (one contiguous memset): degf, cnt, m, den, num
    float* degf = (float*)alloc(NN * 4);
    int*   cnt  = (int*)  alloc(NN * 4);
    float* m    = (float*)alloc(NN * 4);
    float* den  = (float*)alloc(NN * 4);
    float* num  = (float*)alloc(NN * 4);
    size_t zbytes = off;
    // rest (fully overwritten each call)
    float* dis    = (float*)alloc(NN * 4);
    int* indptr   = (int*)  alloc((NN + 1) * 4);
    int* cursor   = (int*)  alloc(NN * 4);
    float* nw     = (float*)alloc(NN * 4);
    int* srt_row  = (int*)  alloc((size_t)NE * 4);
    float* srt_nrm= (float*)alloc((size_t)NE * 4);
    float* bufA   = (float*)alloc((size_t)NN * HD * 4);
    float* bufB   = (float*)alloc((size_t)NN * HD * 4);
    float* sfeat  = (float*)alloc(NB * 128 * 4);
    int* gstart   = (int*)  alloc((NB + 1) * 4);
    (void)ws_size; (void)in_sizes; (void)n_in; (void)out_size;

    const int EB = (NE + 255) / 256;   // 3907
    const int VB = (NN + 255) / 256;   // 391

    hipMemsetAsync(ws, 0, zbytes, stream);
    k_edge1<<<EB, 256, 0, stream>>>(ei, ew, cnt, degf, (unsigned int*)m);
    k_node1<<<VB, 256, 0, stream>>>(degf, dis);
    k_scan<<<1, 1024, 0, stream>>>(cnt, indptr, cursor);
    k_edge2<<<EB, 256, 0, stream>>>(ei, ew, dis, m, cursor, srt_row, srt_nrm, den, num);
    k_node2<<<VB, 256, 0, stream>>>(den, num, nw);

    // layer 1: x -> bufA -> agg -> bufB (leaky relu)
    k_gemm<<<NN / 16, 256, 0, stream>>>(x, W1, bufA);
    k_agg<<<NN / 4, 256, 0, stream>>>(bufA, indptr, srt_row, srt_nrm, dis, b1, bufB, 1);
    // layer 2
    k_gemm<<<NN / 16, 256, 0, stream>>>(bufB, W2, bufA);
    k_agg<<<NN / 4, 256, 0, stream>>>(bufA, indptr, srt_row, srt_nrm, dis, b2, bufB, 1);
    // layer 3 (no activation)
    k_gemm<<<NN / 16, 256, 0, stream>>>(bufB, W3, bufA);
    k_agg<<<NN / 4, 256, 0, stream>>>(bufA, indptr, srt_row, srt_nrm, dis, b3, bufB, 0);

    // pooling + head
    k_gsinit<<<1, 256, 0, stream>>>(gstart);
    k_gsmin<<<VB, 256, 0, stream>>>(batch, gstart);
    k_gsfix<<<1, 1, 0, stream>>>(gstart);
    k_pool<<<NB, 256, 0, stream>>>(bufB, nw, gstart, sfeat, out + 2560);
    k_mlp<<<NB, 128, 0, stream>>>(sfeat, Wlin, blin, Wout, bout, out);
}

// Round 4
// 1174.456 us; speedup vs baseline: 1.2496x; 1.2496x over previous
//
#include <hip/hip_runtime.h>
#include <hip/hip_bf16.h>

#define NN 100000     // nodes
#define NE 1000000    // edges
#define HD 64         // feature dim (F_IN == H == 64)
#define NB 128        // graphs
#define NC 10         // classes
#define NEG_SLOPE 0.01f
#define INV_TEMP 20.0f   // 1/0.05

// ---- pass 1 over edges: in-degree histogram, weighted degree, per-node max(ew) ----
__global__ void k_edge1(const int* __restrict__ ei, const float* __restrict__ ew,
                        int* __restrict__ cnt, float* __restrict__ degf,
                        unsigned int* __restrict__ mmax) {
    int e = blockIdx.x * 256 + threadIdx.x;
    if (e >= NE) return;
    int r = ei[e], c = ei[NE + e];
    float w = ew[e];
    atomicAdd(&cnt[c], 1);
    atomicAdd(&degf[c], w);
    unsigned int wb = __float_as_uint(w);   // ew >= 0 -> uint order == float order
    atomicMax(&mmax[r], wb);
    atomicMax(&mmax[c], wb);
}

// ---- dis = rsqrt(deg), deg includes self-loop weight 1 ----
__global__ void k_node1(const float* __restrict__ degf, float* __restrict__ dis) {
    int i = blockIdx.x * 256 + threadIdx.x;
    if (i < NN) dis[i] = rsqrtf(degf[i] + 1.0f);
}

// ---- single-block exclusive scan of cnt -> indptr, cursor ----
__global__ void k_scan(const int* __restrict__ cnt, int* __restrict__ indptr,
                       int* __restrict__ cursor) {
    __shared__ int sums[1024];
    const int t = threadIdx.x;
    const int PER = (NN + 1023) / 1024;   // 98
    int i0 = t * PER, i1 = min(NN, i0 + PER);
    int s = 0;
    for (int i = i0; i < i1; ++i) s += cnt[i];
    sums[t] = s;
    __syncthreads();
    for (int d = 1; d < 1024; d <<= 1) {
        int v = (t >= d) ? sums[t - d] : 0;
        __syncthreads();
        sums[t] += v;
        __syncthreads();
    }
    int pref = (t == 0) ? 0 : sums[t - 1];
    for (int i = i0; i < i1; ++i) {
        indptr[i] = pref; cursor[i] = pref;
        pref += cnt[i];
    }
    if (t == 0) indptr[NN] = NE;
}

// ---- pass 2 over edges: norm + CSR scatter + smooth-max softmax accumulation ----
__global__ void k_edge2(const int* __restrict__ ei, const float* __restrict__ ew,
                        const float* __restrict__ dis, const float* __restrict__ m,
                        int* __restrict__ cursor, int* __restrict__ srt_row,
                        float* __restrict__ srt_norm,
                        float* __restrict__ den, float* __restrict__ num) {
    int e = blockIdx.x * 256 + threadIdx.x;
    if (e >= NE) return;
    int r = ei[e], c = ei[NE + e];
    float w = ew[e];
    float nrm = dis[r] * w * dis[c];
    int p = atomicAdd(&cursor[c], 1);
    srt_row[p] = r;
    srt_norm[p] = nrm;
    float ar = __expf((w - m[r]) * INV_TEMP);
    atomicAdd(&den[r], ar);
    atomicAdd(&num[r], w * ar);
    float ac = __expf((w - m[c]) * INV_TEMP);
    atomicAdd(&den[c], ac);
    atomicAdd(&num[c], w * ac);
}

// ---- nw = num/den (0 for isolated) ----
__global__ void k_node2(const float* __restrict__ den, const float* __restrict__ num,
                        float* __restrict__ nw) {
    int i = blockIdx.x * 256 + threadIdx.x;
    if (i < NN) {
        float d = den[i];
        nw[i] = (d > 0.f) ? num[i] / fmaxf(d, 1e-16f) : 0.f;
    }
}

// ---- dense GEMM: T[N,64] = Hin[N,64] @ W[64,64]; 16 rows/block ----
__global__ void k_gemm(const float* __restrict__ Hin, const float* __restrict__ W,
                       float* __restrict__ T) {
    __shared__ float Ws[64 * 64];
    __shared__ float Hs[16 * 64];
    int tid = threadIdx.x;
    for (int i = tid; i < 64 * 64; i += 256) Ws[i] = W[i];
    int row0 = blockIdx.x * 16;   // NN % 16 == 0 -> no guard
    for (int i = tid; i < 16 * 64; i += 256)
        Hs[i] = Hin[(row0 + (i >> 6)) * HD + (i & 63)];
    __syncthreads();
    int j = tid & 63, rq = tid >> 6;
    float acc[4] = {0.f, 0.f, 0.f, 0.f};
    for (int k = 0; k < 64; ++k) {
        float wv = Ws[k * 64 + j];
#pragma unroll
        for (int rr = 0; rr < 4; ++rr)
            acc[rr] += Hs[(rq * 4 + rr) * 64 + k] * wv;
    }
#pragma unroll
    for (int rr = 0; rr < 4; ++rr)
        T[(row0 + rq * 4 + rr) * HD + j] = acc[rr];
}

// ---- CSR aggregation: one wave per node, lane = feature ----
__global__ void k_agg(const float* __restrict__ T, const int* __restrict__ indptr,
                      const int* __restrict__ srt_row, const float* __restrict__ srt_norm,
                      const float* __restrict__ dis, const float* __restrict__ bias,
                      float* __restrict__ Hout, int lrelu) {
    int wv = threadIdx.x >> 6, lane = threadIdx.x & 63;
    int node = blockIdx.x * 4 + wv;
    if (node >= NN) return;
    float d = dis[node];
    float acc = bias[lane] + d * d * T[node * HD + lane];   // self-loop
    int beg = indptr[node], end = indptr[node + 1];
    for (int e = beg; e < end; ++e) {
        int r = srt_row[e];
        float nm = srt_norm[e];
        acc += nm * T[r * HD + lane];
    }
    if (lrelu) acc = acc > 0.f ? acc : NEG_SLOPE * acc;
    Hout[node * HD + lane] = acc;
}

// ---- graph boundaries from sorted batch (no atomics) ----
__global__ void k_gsinit(int* __restrict__ gstart) {
    int t = threadIdx.x;
    if (t <= NB) gstart[t] = NN;
}
__global__ void k_gsbound(const int* __restrict__ batch, int* __restrict__ gstart) {
    int n = blockIdx.x * 256 + threadIdx.x;
    if (n >= NN) return;
    int b = batch[n];
    int prev = (n == 0) ? -1 : batch[n - 1];
    if (b != prev) gstart[b] = n;   // batch sorted -> first occurrence, single writer
}
__global__ void k_gsfix(int* __restrict__ gstart) {
    for (int b = NB - 1; b >= 0; --b)
        if (gstart[b] > gstart[b + 1]) gstart[b] = gstart[b + 1];
}

// ---- weighted pooling: one block (4 waves) per graph; fp32 out ----
__global__ void k_pool(const float* __restrict__ H3, const float* __restrict__ nw,
                       const int* __restrict__ gstart, float* __restrict__ sfeat,
                       float* __restrict__ out_feats) {
    __shared__ float sred[4][64];
    __shared__ float wred[4];
    __shared__ float wsum_s;
    int b = blockIdx.x;
    int wv = threadIdx.x >> 6, lane = threadIdx.x & 63;
    int beg = gstart[b], end = gstart[b + 1];
    float accs = 0.f, accw = 0.f;
    for (int n = beg + wv; n < end; n += 4) {
        float wn = nw[n];
        accs += wn * H3[n * HD + lane];
        accw += wn;       // identical across lanes of this wave
    }
    sred[wv][lane] = accs;
    if (lane == 0) wred[wv] = accw;
    __syncthreads();
    if (threadIdx.x < 64) {
        float s = sred[0][lane] + sred[1][lane] + sred[2][lane] + sred[3][lane];
        sred[0][lane] = s;
        if (lane == 0) wsum_s = wred[0] + wred[1] + wred[2] + wred[3];
    }
    __syncthreads();
    if (threadIdx.x < 64) {
        float s = sred[0][lane];
        float mean = s / fmaxf(wsum_s, 1e-16f);
        sfeat[b * 128 + lane] = s;
        sfeat[b * 128 + 64 + lane] = mean;
        out_feats[b * 128 + lane] = s;
        out_feats[b * 128 + 64 + lane] = mean;
    }
}

// ---- head MLP + softmax; one block per graph; fp32 out ----
// out layout (fp32 elements): logits[0,1280) probs[1280,2560) feats[2560,18944)
//                             embeds[18944,27136) hout[27136,35328)
__global__ void k_mlp(const float* __restrict__ sfeat, const float* __restrict__ Wlin,
                      const float* __restrict__ blin, const float* __restrict__ Wout,
                      const float* __restrict__ bout, float* __restrict__ out) {
    __shared__ float fs[128];
    __shared__ float hs[64];
    __shared__ float lg[10];
    int b = blockIdx.x, t = threadIdx.x;   // 128 threads
    fs[t] = sfeat[b * 128 + t];
    __syncthreads();
    if (t < 64) {
        float acc = blin[t];
        for (int k = 0; k < 128; ++k) acc += fs[k] * Wlin[k * 64 + t];
        out[18944 + b * 64 + t] = acc;
        float h = fmaxf(acc, 0.f);
        out[27136 + b * 64 + t] = h;
        hs[t] = h;
    }
    __syncthreads();
    if (t < NC) {
        float acc = bout[t];
        for (int j = 0; j < 64; ++j) acc += hs[j] * Wout[j * NC + t];
        lg[t] = acc;
        out[b * NC + t] = acc;
    }
    __syncthreads();
    if (t < NC) {
        float mx = lg[0];
        for (int k = 1; k < NC; ++k) mx = fmaxf(mx, lg[k]);
        float se = 0.f;
        for (int k = 0; k < NC; ++k) se += __expf(lg[k] - mx);
        float p = __expf(lg[t] - mx) / se;
        out[1280 + b * NC + t] = p;
    }
}

extern "C" void kernel_launch(void* const* d_in, const int* in_sizes, int n_in,
                              void* d_out, int out_size, void* d_ws, size_t ws_size,
                              hipStream_t stream) {
    const float* x    = (const float*)d_in[0];
    const int*   ei   = (const int*)  d_in[1];
    const float* ew   = (const float*)d_in[2];
    const int*   batch= (const int*)  d_in[3];
    const float* W1   = (const float*)d_in[4];
    const float* b1   = (const float*)d_in[5];
    const float* W2   = (const float*)d_in[6];
    const float* b2   = (const float*)d_in[7];
    const float* W3   = (const float*)d_in[8];
    const float* b3   = (const float*)d_in[9];
    const float* Wlin = (const float*)d_in[10];
    const float* blin = (const float*)d_in[11];
    const float* Wout = (const float*)d_in[12];
    const float* bout = (const float*)d_in[13];
    float* out = (float*)d_out;

    char* ws = (char*)d_ws;
    size_t off = 0;
    auto alloc = [&](size_t bytes) -> void* {
        void* p = ws + off;
        off = (off + bytes + 255) & ~(size_t)255;
        return p;
    };
    // zeroed group (one contiguous memset): degf, cnt, m, den, num
    float* degf = (float*)alloc(NN * 4);
    int*   cnt  = (int*)  alloc(NN * 4);
    float* m    = (float*)alloc(NN * 4);
    float* den  = (float*)alloc(NN * 4);
    float* num  = (float*)alloc(NN * 4);
    size_t zbytes = off;
    // rest (fully overwritten each call)
    float* dis    = (float*)alloc(NN * 4);
    int* indptr   = (int*)  alloc((NN + 1) * 4);
    int* cursor   = (int*)  alloc(NN * 4);
    float* nw     = (float*)alloc(NN * 4);
    int* srt_row  = (int*)  alloc((size_t)NE * 4);
    float* srt_nrm= (float*)alloc((size_t)NE * 4);
    float* bufA   = (float*)alloc((size_t)NN * HD * 4);
    float* bufB   = (float*)alloc((size_t)NN * HD * 4);
    float* sfeat  = (float*)alloc(NB * 128 * 4);
    int* gstart   = (int*)  alloc((NB + 1) * 4);
    (void)ws_size; (void)in_sizes; (void)n_in; (void)out_size;

    const int EB = (NE + 255) / 256;   // 3907
    const int VB = (NN + 255) / 256;   // 391

    hipMemsetAsync(ws, 0, zbytes, stream);
    k_edge1<<<EB, 256, 0, stream>>>(ei, ew, cnt, degf, (unsigned int*)m);
    k_node1<<<VB, 256, 0, stream>>>(degf, dis);
    k_scan<<<1, 1024, 0, stream>>>(cnt, indptr, cursor);
    k_edge2<<<EB, 256, 0, stream>>>(ei, ew, dis, m, cursor, srt_row, srt_nrm, den, num);
    k_node2<<<VB, 256, 0, stream>>>(den, num, nw);

    // layer 1: x -> bufA -> agg -> bufB (leaky relu)
    k_gemm<<<NN / 16, 256, 0, stream>>>(x, W1, bufA);
    k_agg<<<NN / 4, 256, 0, stream>>>(bufA, indptr, srt_row, srt_nrm, dis, b1, bufB, 1);
    // layer 2
    k_gemm<<<NN / 16, 256, 0, stream>>>(bufB, W2, bufA);
    k_agg<<<NN / 4, 256, 0, stream>>>(bufA, indptr, srt_row, srt_nrm, dis, b2, bufB, 1);
    // layer 3 (no activation)
    k_gemm<<<NN / 16, 256, 0, stream>>>(bufB, W3, bufA);
    k_agg<<<NN / 4, 256, 0, stream>>>(bufA, indptr, srt_row, srt_nrm, dis, b3, bufB, 0);

    // pooling + head
    k_gsinit<<<1, 256, 0, stream>>>(gstart);
    k_gsbound<<<VB, 256, 0, stream>>>(batch, gstart);
    k_gsfix<<<1, 1, 0, stream>>>(gstart);
    k_pool<<<NB, 256, 0, stream>>>(bufB, nw, gstart, sfeat, out + 2560);
    k_mlp<<<NB, 128, 0, stream>>>(sfeat, Wlin, blin, Wout, bout, out);
}

// Round 5
// 736.722 us; speedup vs baseline: 1.9921x; 1.5942x over previous
//
#include <hip/hip_runtime.h>
#include <hip/hip_bf16.h>

#define NN 100000     // nodes
#define NE 1000000    // edges
#define HD 64         // feature dim (F_IN == H == 64)
#define NB 128        // graphs
#define NC 10         // classes
#define NEG_SLOPE 0.01f
#define INV_TEMP 20.0f   // 1/0.05

// ---- pass 1 over edges: in-degree histogram + weighted degree ----
// (segment-max removed: num/den softmax ratio is shift-invariant and
//  e^(20w) <= 4.9e8 for w in [0,1) -- no overflow in fp32)
__global__ void k_edge1(const int* __restrict__ ei, const float* __restrict__ ew,
                        int* __restrict__ cnt, float* __restrict__ degf) {
    int e = blockIdx.x * 256 + threadIdx.x;
    if (e >= NE) return;
    int c = ei[NE + e];
    float w = ew[e];
    atomicAdd(&cnt[c], 1);
    atomicAdd(&degf[c], w);
}

// ---- dis = rsqrt(deg), deg includes self-loop weight 1 ----
__global__ void k_node1(const float* __restrict__ degf, float* __restrict__ dis) {
    int i = blockIdx.x * 256 + threadIdx.x;
    if (i < NN) dis[i] = rsqrtf(degf[i] + 1.0f);
}

// ---- multi-block exclusive scan of cnt -> indptr, cursor ----
__global__ void k_scan1(const int* __restrict__ cnt, int* __restrict__ bsum) {
    __shared__ int red[4];
    int i = blockIdx.x * 256 + threadIdx.x;
    int v = (i < NN) ? cnt[i] : 0;
    for (int o = 32; o > 0; o >>= 1) v += __shfl_down(v, o, 64);
    if ((threadIdx.x & 63) == 0) red[threadIdx.x >> 6] = v;
    __syncthreads();
    if (threadIdx.x == 0) bsum[blockIdx.x] = red[0] + red[1] + red[2] + red[3];
}
__global__ void k_scan2(int* __restrict__ bsum, int nblk) {
    __shared__ int s[512];
    int t = threadIdx.x;
    int v = (t < nblk) ? bsum[t] : 0;
    s[t] = v;
    __syncthreads();
    for (int d = 1; d < 512; d <<= 1) {
        int u = (t >= d) ? s[t - d] : 0;
        __syncthreads();
        s[t] += u;
        __syncthreads();
    }
    if (t < nblk) bsum[t] = s[t] - v;   // exclusive
}
__global__ void k_scan3(const int* __restrict__ cnt, const int* __restrict__ bsum,
                        int* __restrict__ indptr, int* __restrict__ cursor) {
    __shared__ int s[256];
    int t = threadIdx.x;
    int i = blockIdx.x * 256 + t;
    int v = (i < NN) ? cnt[i] : 0;
    s[t] = v;
    __syncthreads();
    for (int d = 1; d < 256; d <<= 1) {
        int u = (t >= d) ? s[t - d] : 0;
        __syncthreads();
        s[t] += u;
        __syncthreads();
    }
    int excl = s[t] - v + bsum[blockIdx.x];
    if (i < NN) { indptr[i] = excl; cursor[i] = excl; }
    if (i == NN - 1) indptr[NN] = NE;
}

// ---- pass 2 over edges: norm + packed CSR scatter + softmax accumulation ----
__global__ void k_edge2(const int* __restrict__ ei, const float* __restrict__ ew,
                        const float* __restrict__ dis,
                        int* __restrict__ cursor, int2* __restrict__ srt,
                        float* __restrict__ den, float* __restrict__ num) {
    int e = blockIdx.x * 256 + threadIdx.x;
    if (e >= NE) return;
    int r = ei[e], c = ei[NE + e];
    float w = ew[e];
    float nrm = dis[r] * w * dis[c];
    int p = atomicAdd(&cursor[c], 1);
    int2 pk; pk.x = r; pk.y = __float_as_int(nrm);
    srt[p] = pk;                                   // one 8B scattered store
    float a = __expf(w * INV_TEMP);                // same for both endpoints
    atomicAdd(&den[r], a);
    atomicAdd(&num[r], w * a);
    atomicAdd(&den[c], a);
    atomicAdd(&num[c], w * a);
}

// ---- nw = num/den (0 for isolated) ----
__global__ void k_node2(const float* __restrict__ den, const float* __restrict__ num,
                        float* __restrict__ nw) {
    int i = blockIdx.x * 256 + threadIdx.x;
    if (i < NN) {
        float d = den[i];
        nw[i] = (d > 0.f) ? num[i] / fmaxf(d, 1e-16f) : 0.f;
    }
}

// ---- dense GEMM: T[N,64] = Hin[N,64] @ W[64,64]; 16 rows/block ----
__global__ void k_gemm(const float* __restrict__ Hin, const float* __restrict__ W,
                       float* __restrict__ T) {
    __shared__ float Ws[64 * 64];
    __shared__ float Hs[16 * 64];
    int tid = threadIdx.x;
    const float4* W4 = (const float4*)W;
    float4* Ws4 = (float4*)Ws;
#pragma unroll
    for (int i = 0; i < 4; ++i) Ws4[tid + i * 256] = W4[tid + i * 256];
    int row0 = blockIdx.x * 16;   // NN % 16 == 0 -> no guard
    const float4* H4 = (const float4*)(Hin + (size_t)row0 * HD);
    ((float4*)Hs)[tid] = H4[tid];
    __syncthreads();
    int j = tid & 63, rq = tid >> 6;
    float acc[4] = {0.f, 0.f, 0.f, 0.f};
    for (int k = 0; k < 64; ++k) {
        float wv = Ws[k * 64 + j];
#pragma unroll
        for (int rr = 0; rr < 4; ++rr)
            acc[rr] += Hs[(rq * 4 + rr) * 64 + k] * wv;
    }
#pragma unroll
    for (int rr = 0; rr < 4; ++rr)
        T[(row0 + rq * 4 + rr) * HD + j] = acc[rr];
}

// ---- CSR aggregation: one wave per node, lane = feature; 4x ILP unroll ----
__global__ void k_agg(const float* __restrict__ T, const int* __restrict__ indptr,
                      const int2* __restrict__ srt,
                      const float* __restrict__ dis, const float* __restrict__ bias,
                      float* __restrict__ Hout, int lrelu) {
    int wv = threadIdx.x >> 6, lane = threadIdx.x & 63;
    int node = blockIdx.x * 4 + wv;
    if (node >= NN) return;
    float d = dis[node];
    float acc = bias[lane] + d * d * T[node * HD + lane];   // self-loop
    int beg = indptr[node], end = indptr[node + 1];
    int e = beg;
    for (; e + 4 <= end; e += 4) {
        int2 p0 = srt[e], p1 = srt[e + 1], p2 = srt[e + 2], p3 = srt[e + 3];
        float v0 = T[p0.x * HD + lane];
        float v1 = T[p1.x * HD + lane];
        float v2 = T[p2.x * HD + lane];
        float v3 = T[p3.x * HD + lane];
        acc += __int_as_float(p0.y) * v0;
        acc += __int_as_float(p1.y) * v1;
        acc += __int_as_float(p2.y) * v2;
        acc += __int_as_float(p3.y) * v3;
    }
    for (; e < end; ++e) {
        int2 p = srt[e];
        acc += __int_as_float(p.y) * T[p.x * HD + lane];
    }
    if (lrelu) acc = acc > 0.f ? acc : NEG_SLOPE * acc;
    Hout[node * HD + lane] = acc;
}

// ---- graph boundaries from sorted batch (no atomics) ----
__global__ void k_gsinit(int* __restrict__ gstart) {
    int t = threadIdx.x;
    if (t <= NB) gstart[t] = NN;
}
__global__ void k_gsbound(const int* __restrict__ batch, int* __restrict__ gstart) {
    int n = blockIdx.x * 256 + threadIdx.x;
    if (n >= NN) return;
    int b = batch[n];
    int prev = (n == 0) ? -1 : batch[n - 1];
    if (b != prev) gstart[b] = n;   // batch sorted -> first occurrence, single writer
}
__global__ void k_gsfix(int* __restrict__ gstart) {
    for (int b = NB - 1; b >= 0; --b)
        if (gstart[b] > gstart[b + 1]) gstart[b] = gstart[b + 1];
}

// ---- weighted pooling: one block (4 waves) per graph; fp32 out ----
__global__ void k_pool(const float* __restrict__ H3, const float* __restrict__ nw,
                       const int* __restrict__ gstart, float* __restrict__ sfeat,
                       float* __restrict__ out_feats) {
    __shared__ float sred[4][64];
    __shared__ float wred[4];
    __shared__ float wsum_s;
    int b = blockIdx.x;
    int wv = threadIdx.x >> 6, lane = threadIdx.x & 63;
    int beg = gstart[b], end = gstart[b + 1];
    float accs = 0.f, accw = 0.f;
    for (int n = beg + wv; n < end; n += 4) {
        float wn = nw[n];
        accs += wn * H3[n * HD + lane];
        accw += wn;       // identical across lanes of this wave
    }
    sred[wv][lane] = accs;
    if (lane == 0) wred[wv] = accw;
    __syncthreads();
    if (threadIdx.x < 64) {
        float s = sred[0][lane] + sred[1][lane] + sred[2][lane] + sred[3][lane];
        sred[0][lane] = s;
        if (lane == 0) wsum_s = wred[0] + wred[1] + wred[2] + wred[3];
    }
    __syncthreads();
    if (threadIdx.x < 64) {
        float s = sred[0][lane];
        float mean = s / fmaxf(wsum_s, 1e-16f);
        sfeat[b * 128 + lane] = s;
        sfeat[b * 128 + 64 + lane] = mean;
        out_feats[b * 128 + lane] = s;
        out_feats[b * 128 + 64 + lane] = mean;
    }
}

// ---- head MLP + softmax; one block per graph; fp32 out ----
// out layout (fp32 elements): logits[0,1280) probs[1280,2560) feats[2560,18944)
//                             embeds[18944,27136) hout[27136,35328)
__global__ void k_mlp(const float* __restrict__ sfeat, const float* __restrict__ Wlin,
                      const float* __restrict__ blin, const float* __restrict__ Wout,
                      const float* __restrict__ bout, float* __restrict__ out) {
    __shared__ float fs[128];
    __shared__ float hs[64];
    __shared__ float lg[10];
    int b = blockIdx.x, t = threadIdx.x;   // 128 threads
    fs[t] = sfeat[b * 128 + t];
    __syncthreads();
    if (t < 64) {
        float acc = blin[t];
        for (int k = 0; k < 128; ++k) acc += fs[k] * Wlin[k * 64 + t];
        out[18944 + b * 64 + t] = acc;
        float h = fmaxf(acc, 0.f);
        out[27136 + b * 64 + t] = h;
        hs[t] = h;
    }
    __syncthreads();
    if (t < NC) {
        float acc = bout[t];
        for (int j = 0; j < 64; ++j) acc += hs[j] * Wout[j * NC + t];
        lg[t] = acc;
        out[b * NC + t] = acc;
    }
    __syncthreads();
    if (t < NC) {
        float mx = lg[0];
        for (int k = 1; k < NC; ++k) mx = fmaxf(mx, lg[k]);
        float se = 0.f;
        for (int k = 0; k < NC; ++k) se += __expf(lg[k] - mx);
        float p = __expf(lg[t] - mx) / se;
        out[1280 + b * NC + t] = p;
    }
}

extern "C" void kernel_launch(void* const* d_in, const int* in_sizes, int n_in,
                              void* d_out, int out_size, void* d_ws, size_t ws_size,
                              hipStream_t stream) {
    const float* x    = (const float*)d_in[0];
    const int*   ei   = (const int*)  d_in[1];
    const float* ew   = (const float*)d_in[2];
    const int*   batch= (const int*)  d_in[3];
    const float* W1   = (const float*)d_in[4];
    const float* b1   = (const float*)d_in[5];
    const float* W2   = (const float*)d_in[6];
    const float* b2   = (const float*)d_in[7];
    const float* W3   = (const float*)d_in[8];
    const float* b3   = (const float*)d_in[9];
    const float* Wlin = (const float*)d_in[10];
    const float* blin = (const float*)d_in[11];
    const float* Wout = (const float*)d_in[12];
    const float* bout = (const float*)d_in[13];
    float* out = (float*)d_out;

    char* ws = (char*)d_ws;
    size_t off = 0;
    auto alloc = [&](size_t bytes) -> void* {
        void* p = ws + off;
        off = (off + bytes + 255) & ~(size_t)255;
        return p;
    };
    // zeroed group (one contiguous memset): degf, cnt, den, num
    float* degf = (float*)alloc(NN * 4);
    int*   cnt  = (int*)  alloc(NN * 4);
    float* den  = (float*)alloc(NN * 4);
    float* num  = (float*)alloc(NN * 4);
    size_t zbytes = off;
    // rest (fully overwritten each call)
    float* dis    = (float*)alloc(NN * 4);
    int* indptr   = (int*)  alloc((NN + 1) * 4);
    int* cursor   = (int*)  alloc(NN * 4);
    float* nw     = (float*)alloc(NN * 4);
    int* bsum     = (int*)  alloc(512 * 4);
    int2* srt     = (int2*) alloc((size_t)NE * 8);
    float* bufA   = (float*)alloc((size_t)NN * HD * 4);
    float* bufB   = (float*)alloc((size_t)NN * HD * 4);
    float* sfeat  = (float*)alloc(NB * 128 * 4);
    int* gstart   = (int*)  alloc((NB + 1) * 4);
    (void)ws_size; (void)in_sizes; (void)n_in; (void)out_size;

    const int EB = (NE + 255) / 256;   // 3907
    const int VB = (NN + 255) / 256;   // 391

    hipMemsetAsync(ws, 0, zbytes, stream);
    k_edge1<<<EB, 256, 0, stream>>>(ei, ew, cnt, degf);
    k_node1<<<VB, 256, 0, stream>>>(degf, dis);
    k_scan1<<<VB, 256, 0, stream>>>(cnt, bsum);
    k_scan2<<<1, 512, 0, stream>>>(bsum, VB);
    k_scan3<<<VB, 256, 0, stream>>>(cnt, bsum, indptr, cursor);
    k_edge2<<<EB, 256, 0, stream>>>(ei, ew, dis, cursor, srt, den, num);
    k_node2<<<VB, 256, 0, stream>>>(den, num, nw);

    // layer 1: x -> bufA -> agg -> bufB (leaky relu)
    k_gemm<<<NN / 16, 256, 0, stream>>>(x, W1, bufA);
    k_agg<<<NN / 4, 256, 0, stream>>>(bufA, indptr, srt, dis, b1, bufB, 1);
    // layer 2
    k_gemm<<<NN / 16, 256, 0, stream>>>(bufB, W2, bufA);
    k_agg<<<NN / 4, 256, 0, stream>>>(bufA, indptr, srt, dis, b2, bufB, 1);
    // layer 3 (no activation)
    k_gemm<<<NN / 16, 256, 0, stream>>>(bufB, W3, bufA);
    k_agg<<<NN / 4, 256, 0, stream>>>(bufA, indptr, srt, dis, b3, bufB, 0);

    // pooling + head
    k_gsinit<<<1, 256, 0, stream>>>(gstart);
    k_gsbound<<<VB, 256, 0, stream>>>(batch, gstart);
    k_gsfix<<<1, 1, 0, stream>>>(gstart);
    k_pool<<<NB, 256, 0, stream>>>(bufB, nw, gstart, sfeat, out + 2560);
    k_mlp<<<NB, 128, 0, stream>>>(sfeat, Wlin, blin, Wout, bout, out);
}

// Round 6
// 597.730 us; speedup vs baseline: 2.4553x; 1.2325x over previous
//
#include <hip/hip_runtime.h>
#include <hip/hip_bf16.h>

#define NN 100000     // nodes
#define NE 1000000    // edges
#define HD 64         // feature dim (F_IN == H == 64)
#define NB 128        // graphs
#define NC 10         // classes
#define NEG_SLOPE 0.01f
#define INV_TEMP 20.0f   // 1/0.05

// ---- pass 1: in-degree histogram only (1M int atomics) ----
__global__ void k_edge1(const int* __restrict__ ei, int* __restrict__ cnt) {
    int e = blockIdx.x * 256 + threadIdx.x;
    if (e >= NE) return;
    atomicAdd(&cnt[ei[NE + e]], 1);
}

// ---- multi-block exclusive scan of cnt -> indptr, cursor ----
__global__ void k_scan1(const int* __restrict__ cnt, int* __restrict__ bsum) {
    __shared__ int red[4];
    int i = blockIdx.x * 256 + threadIdx.x;
    int v = (i < NN) ? cnt[i] : 0;
    for (int o = 32; o > 0; o >>= 1) v += __shfl_down(v, o, 64);
    if ((threadIdx.x & 63) == 0) red[threadIdx.x >> 6] = v;
    __syncthreads();
    if (threadIdx.x == 0) bsum[blockIdx.x] = red[0] + red[1] + red[2] + red[3];
}
// also initializes gstart defaults (folded from old k_gsinit)
__global__ void k_scan2(int* __restrict__ bsum, int nblk, int* __restrict__ gstart) {
    __shared__ int s[512];
    int t = threadIdx.x;
    if (t <= NB) gstart[t] = NN;
    int v = (t < nblk) ? bsum[t] : 0;
    s[t] = v;
    __syncthreads();
    for (int d = 1; d < 512; d <<= 1) {
        int u = (t >= d) ? s[t - d] : 0;
        __syncthreads();
        s[t] += u;
        __syncthreads();
    }
    if (t < nblk) bsum[t] = s[t] - v;   // exclusive
}
__global__ void k_scan3(const int* __restrict__ cnt, const int* __restrict__ bsum,
                        int* __restrict__ indptr, int* __restrict__ cursor) {
    __shared__ int s[256];
    int t = threadIdx.x;
    int i = blockIdx.x * 256 + t;
    int v = (i < NN) ? cnt[i] : 0;
    s[t] = v;
    __syncthreads();
    for (int d = 1; d < 256; d <<= 1) {
        int u = (t >= d) ? s[t - d] : 0;
        __syncthreads();
        s[t] += u;
        __syncthreads();
    }
    int excl = s[t] - v + bsum[blockIdx.x];
    if (i < NN) { indptr[i] = excl; cursor[i] = excl; }
    if (i == NN - 1) indptr[NN] = NE;
}

// ---- pass 2: CSR scatter of (row, w) + row-side softmax atomics ----
__global__ void k_edge2(const int* __restrict__ ei, const float* __restrict__ ew,
                        int* __restrict__ cursor, int2* __restrict__ srt,
                        float* __restrict__ den, float* __restrict__ num) {
    int e = blockIdx.x * 256 + threadIdx.x;
    if (e >= NE) return;
    int r = ei[e], c = ei[NE + e];
    float w = ew[e];
    int p = atomicAdd(&cursor[c], 1);
    int2 pk; pk.x = r; pk.y = __float_as_int(w);
    srt[p] = pk;                       // one 8B scattered store
    float a = __expf(w * INV_TEMP);    // row-side contribution via atomics;
    atomicAdd(&den[r], a);             // col-side comes from the CSR in k_nodeA
    atomicAdd(&num[r], w * a);
}

// ---- node pass over CSR: degf -> dis, col-side den/num -> nw ----
__global__ void k_nodeA(const int* __restrict__ indptr, const int2* __restrict__ srt,
                        const float* __restrict__ den, const float* __restrict__ num,
                        float* __restrict__ dis, float* __restrict__ nw) {
    int i = blockIdx.x * 256 + threadIdx.x;
    if (i >= NN) return;
    int beg = indptr[i], end = indptr[i + 1];
    float sumw = 0.f, dcol = 0.f, ncol = 0.f;
    for (int e = beg; e < end; ++e) {
        float w = __int_as_float(srt[e].y);
        float a = __expf(w * INV_TEMP);
        sumw += w;
        dcol += a;
        ncol += w * a;
    }
    dis[i] = rsqrtf(sumw + 1.0f);      // +1 = self-loop weight
    float D = den[i] + dcol;
    float Nm = num[i] + ncol;
    nw[i] = (D > 0.f) ? Nm / fmaxf(D, 1e-16f) : 0.f;
}

// ---- dense GEMM: T[N,64] = Hin[N,64] @ W[64,64]; 16 rows/block ----
__global__ void k_gemm(const float* __restrict__ Hin, const float* __restrict__ W,
                       float* __restrict__ T) {
    __shared__ float Ws[64 * 64];
    __shared__ float Hs[16 * 64];
    int tid = threadIdx.x;
    const float4* W4 = (const float4*)W;
    float4* Ws4 = (float4*)Ws;
#pragma unroll
    for (int i = 0; i < 4; ++i) Ws4[tid + i * 256] = W4[tid + i * 256];
    int row0 = blockIdx.x * 16;   // NN % 16 == 0 -> no guard
    const float4* H4 = (const float4*)(Hin + (size_t)row0 * HD);
    ((float4*)Hs)[tid] = H4[tid];
    __syncthreads();
    int j = tid & 63, rq = tid >> 6;
    float acc[4] = {0.f, 0.f, 0.f, 0.f};
    for (int k = 0; k < 64; ++k) {
        float wv = Ws[k * 64 + j];
#pragma unroll
        for (int rr = 0; rr < 4; ++rr)
            acc[rr] += Hs[(rq * 4 + rr) * 64 + k] * wv;
    }
#pragma unroll
    for (int rr = 0; rr < 4; ++rr)
        T[(row0 + rq * 4 + rr) * HD + j] = acc[rr];
}

// ---- CSR aggregation: one wave per node, lane = feature; 4x ILP unroll ----
// norm computed on the fly: dis[r]*w*dis[c], with dis[c] factored out
__global__ void k_agg(const float* __restrict__ T, const int* __restrict__ indptr,
                      const int2* __restrict__ srt,
                      const float* __restrict__ dis, const float* __restrict__ bias,
                      float* __restrict__ Hout, int lrelu) {
    int wv = threadIdx.x >> 6, lane = threadIdx.x & 63;
    int node = blockIdx.x * 4 + wv;
    if (node >= NN) return;
    float d = dis[node];
    float self = T[node * HD + lane];
    float acc = 0.f;
    int beg = indptr[node], end = indptr[node + 1];
    int e = beg;
    for (; e + 4 <= end; e += 4) {
        int2 p0 = srt[e], p1 = srt[e + 1], p2 = srt[e + 2], p3 = srt[e + 3];
        float s0 = dis[p0.x] * __int_as_float(p0.y);
        float s1 = dis[p1.x] * __int_as_float(p1.y);
        float s2 = dis[p2.x] * __int_as_float(p2.y);
        float s3 = dis[p3.x] * __int_as_float(p3.y);
        acc += s0 * T[p0.x * HD + lane];
        acc += s1 * T[p1.x * HD + lane];
        acc += s2 * T[p2.x * HD + lane];
        acc += s3 * T[p3.x * HD + lane];
    }
    for (; e < end; ++e) {
        int2 p = srt[e];
        acc += dis[p.x] * __int_as_float(p.y) * T[p.x * HD + lane];
    }
    float res = bias[lane] + d * (d * self + acc);
    if (lrelu) res = res > 0.f ? res : NEG_SLOPE * res;
    Hout[node * HD + lane] = res;
}

// ---- graph boundaries from sorted batch (no atomics) ----
__global__ void k_gsbound(const int* __restrict__ batch, int* __restrict__ gstart) {
    int n = blockIdx.x * 256 + threadIdx.x;
    if (n >= NN) return;
    int b = batch[n];
    int prev = (n == 0) ? -1 : batch[n - 1];
    if (b != prev) gstart[b] = n;   // batch sorted -> first occurrence, single writer
}

// ---- weighted pooling: one block (4 waves) per graph; suffix-min boundary fix ----
__global__ void k_pool(const float* __restrict__ H3, const float* __restrict__ nw,
                       const int* __restrict__ gstart, float* __restrict__ sfeat,
                       float* __restrict__ out_feats) {
    __shared__ float sred[4][64];
    __shared__ float wred[4];
    __shared__ float wsum_s;
    __shared__ int sbeg, send;
    int b = blockIdx.x;
    if (threadIdx.x == 0) {            // suffix-min fix for empty graphs
        int mn = NN;
        for (int j = NB; j > b; --j) mn = min(mn, gstart[j]);
        send = mn;
        sbeg = min(mn, gstart[b]);
    }
    __syncthreads();
    int wv = threadIdx.x >> 6, lane = threadIdx.x & 63;
    int beg = sbeg, end = send;
    float accs = 0.f, accw = 0.f;
    for (int n = beg + wv; n < end; n += 4) {
        float wn = nw[n];
        accs += wn * H3[n * HD + lane];
        accw += wn;       // identical across lanes of this wave
    }
    sred[wv][lane] = accs;
    if (lane == 0) wred[wv] = accw;
    __syncthreads();
    if (threadIdx.x < 64) {
        float s = sred[0][lane] + sred[1][lane] + sred[2][lane] + sred[3][lane];
        sred[0][lane] = s;
        if (lane == 0) wsum_s = wred[0] + wred[1] + wred[2] + wred[3];
    }
    __syncthreads();
    if (threadIdx.x < 64) {
        float s = sred[0][lane];
        float mean = s / fmaxf(wsum_s, 1e-16f);
        sfeat[b * 128 + lane] = s;
        sfeat[b * 128 + 64 + lane] = mean;
        out_feats[b * 128 + lane] = s;
        out_feats[b * 128 + 64 + lane] = mean;
    }
}

// ---- head MLP + softmax; one block per graph; fp32 out ----
// out layout (fp32 elements): logits[0,1280) probs[1280,2560) feats[2560,18944)
//                             embeds[18944,27136) hout[27136,35328)
__global__ void k_mlp(const float* __restrict__ sfeat, const float* __restrict__ Wlin,
                      const float* __restrict__ blin, const float* __restrict__ Wout,
                      const float* __restrict__ bout, float* __restrict__ out) {
    __shared__ float fs[128];
    __shared__ float hs[64];
    __shared__ float lg[10];
    int b = blockIdx.x, t = threadIdx.x;   // 128 threads
    fs[t] = sfeat[b * 128 + t];
    __syncthreads();
    if (t < 64) {
        float acc = blin[t];
        for (int k = 0; k < 128; ++k) acc += fs[k] * Wlin[k * 64 + t];
        out[18944 + b * 64 + t] = acc;
        float h = fmaxf(acc, 0.f);
        out[27136 + b * 64 + t] = h;
        hs[t] = h;
    }
    __syncthreads();
    if (t < NC) {
        float acc = bout[t];
        for (int j = 0; j < 64; ++j) acc += hs[j] * Wout[j * NC + t];
        lg[t] = acc;
        out[b * NC + t] = acc;
    }
    __syncthreads();
    if (t < NC) {
        float mx = lg[0];
        for (int k = 1; k < NC; ++k) mx = fmaxf(mx, lg[k]);
        float se = 0.f;
        for (int k = 0; k < NC; ++k) se += __expf(lg[k] - mx);
        float p = __expf(lg[t] - mx) / se;
        out[1280 + b * NC + t] = p;
    }
}

extern "C" void kernel_launch(void* const* d_in, const int* in_sizes, int n_in,
                              void* d_out, int out_size, void* d_ws, size_t ws_size,
                              hipStream_t stream) {
    const float* x    = (const float*)d_in[0];
    const int*   ei   = (const int*)  d_in[1];
    const float* ew   = (const float*)d_in[2];
    const int*   batch= (const int*)  d_in[3];
    const float* W1   = (const float*)d_in[4];
    const float* b1   = (const float*)d_in[5];
    const float* W2   = (const float*)d_in[6];
    const float* b2   = (const float*)d_in[7];
    const float* W3   = (const float*)d_in[8];
    const float* b3   = (const float*)d_in[9];
    const float* Wlin = (const float*)d_in[10];
    const float* blin = (const float*)d_in[11];
    const float* Wout = (const float*)d_in[12];
    const float* bout = (const float*)d_in[13];
    float* out = (float*)d_out;

    char* ws = (char*)d_ws;
    size_t off = 0;
    auto alloc = [&](size_t bytes) -> void* {
        void* p = ws + off;
        off = (off + bytes + 255) & ~(size_t)255;
        return p;
    };
    // zeroed group (one contiguous memset): cnt, den, num
    int*   cnt  = (int*)  alloc(NN * 4);
    float* den  = (float*)alloc(NN * 4);
    float* num  = (float*)alloc(NN * 4);
    size_t zbytes = off;
    // rest (fully overwritten each call)
    float* dis    = (float*)alloc(NN * 4);
    int* indptr   = (int*)  alloc((NN + 1) * 4);
    int* cursor   = (int*)  alloc(NN * 4);
    float* nw     = (float*)alloc(NN * 4);
    int* bsum     = (int*)  alloc(512 * 4);
    int2* srt     = (int2*) alloc((size_t)NE * 8);
    float* bufA   = (float*)alloc((size_t)NN * HD * 4);
    float* bufB   = (float*)alloc((size_t)NN * HD * 4);
    float* sfeat  = (float*)alloc(NB * 128 * 4);
    int* gstart   = (int*)  alloc((NB + 1) * 4);
    (void)ws_size; (void)in_sizes; (void)n_in; (void)out_size;

    const int EB = (NE + 255) / 256;   // 3907
    const int VB = (NN + 255) / 256;   // 391

    hipMemsetAsync(ws, 0, zbytes, stream);
    k_edge1<<<EB, 256, 0, stream>>>(ei, cnt);
    k_scan1<<<VB, 256, 0, stream>>>(cnt, bsum);
    k_scan2<<<1, 512, 0, stream>>>(bsum, VB, gstart);
    k_scan3<<<VB, 256, 0, stream>>>(cnt, bsum, indptr, cursor);
    k_edge2<<<EB, 256, 0, stream>>>(ei, ew, cursor, srt, den, num);
    k_nodeA<<<VB, 256, 0, stream>>>(indptr, srt, den, num, dis, nw);
    k_gsbound<<<VB, 256, 0, stream>>>(batch, gstart);

    // layer 1: x -> bufA -> agg -> bufB (leaky relu)
    k_gemm<<<NN / 16, 256, 0, stream>>>(x, W1, bufA);
    k_agg<<<NN / 4, 256, 0, stream>>>(bufA, indptr, srt, dis, b1, bufB, 1);
    // layer 2
    k_gemm<<<NN / 16, 256, 0, stream>>>(bufB, W2, bufA);
    k_agg<<<NN / 4, 256, 0, stream>>>(bufA, indptr, srt, dis, b2, bufB, 1);
    // layer 3 (no activation)
    k_gemm<<<NN / 16, 256, 0, stream>>>(bufB, W3, bufA);
    k_agg<<<NN / 4, 256, 0, stream>>>(bufA, indptr, srt, dis, b3, bufB, 0);

    // pooling + head
    k_pool<<<NB, 256, 0, stream>>>(bufB, nw, gstart, sfeat, out + 2560);
    k_mlp<<<NB, 128, 0, stream>>>(sfeat, Wlin, blin, Wout, bout, out);
}

// Round 7
// 588.066 us; speedup vs baseline: 2.4956x; 1.0164x over previous
//
#include <hip/hip_runtime.h>
#include <hip/hip_bf16.h>

typedef __hip_bfloat16 bf16;

#define NN 100000     // nodes
#define NE 1000000    // edges
#define HD 64         // feature dim (F_IN == H == 64)
#define NB 128        // graphs
#define NC 10         // classes
#define NEG_SLOPE 0.01f
#define INV_TEMP 20.0f   // 1/0.05

__device__ __forceinline__ float b2f(bf16 v) { return __bfloat162float(v); }

// ---- pass 1: in-degree histogram only (1M int atomics) ----
__global__ void k_edge1(const int* __restrict__ ei, int* __restrict__ cnt) {
    int e = blockIdx.x * 256 + threadIdx.x;
    if (e >= NE) return;
    atomicAdd(&cnt[ei[NE + e]], 1);
}

// ---- multi-block exclusive scan of cnt -> indptr, cursor ----
__global__ void k_scan1(const int* __restrict__ cnt, int* __restrict__ bsum) {
    __shared__ int red[4];
    int i = blockIdx.x * 256 + threadIdx.x;
    int v = (i < NN) ? cnt[i] : 0;
    for (int o = 32; o > 0; o >>= 1) v += __shfl_down(v, o, 64);
    if ((threadIdx.x & 63) == 0) red[threadIdx.x >> 6] = v;
    __syncthreads();
    if (threadIdx.x == 0) bsum[blockIdx.x] = red[0] + red[1] + red[2] + red[3];
}
// also initializes gstart defaults (folded from old k_gsinit)
__global__ void k_scan2(int* __restrict__ bsum, int nblk, int* __restrict__ gstart) {
    __shared__ int s[512];
    int t = threadIdx.x;
    if (t <= NB) gstart[t] = NN;
    int v = (t < nblk) ? bsum[t] : 0;
    s[t] = v;
    __syncthreads();
    for (int d = 1; d < 512; d <<= 1) {
        int u = (t >= d) ? s[t - d] : 0;
        __syncthreads();
        s[t] += u;
        __syncthreads();
    }
    if (t < nblk) bsum[t] = s[t] - v;   // exclusive
}
__global__ void k_scan3(const int* __restrict__ cnt, const int* __restrict__ bsum,
                        int* __restrict__ indptr, int* __restrict__ cursor) {
    __shared__ int s[256];
    int t = threadIdx.x;
    int i = blockIdx.x * 256 + t;
    int v = (i < NN) ? cnt[i] : 0;
    s[t] = v;
    __syncthreads();
    for (int d = 1; d < 256; d <<= 1) {
        int u = (t >= d) ? s[t - d] : 0;
        __syncthreads();
        s[t] += u;
        __syncthreads();
    }
    int excl = s[t] - v + bsum[blockIdx.x];
    if (i < NN) { indptr[i] = excl; cursor[i] = excl; }
    if (i == NN - 1) indptr[NN] = NE;
}

// ---- pass 2: CSR scatter of (row, w) + row-side softmax atomics ----
__global__ void k_edge2(const int* __restrict__ ei, const float* __restrict__ ew,
                        int* __restrict__ cursor, int2* __restrict__ srt,
                        float* __restrict__ den, float* __restrict__ num) {
    int e = blockIdx.x * 256 + threadIdx.x;
    if (e >= NE) return;
    int r = ei[e], c = ei[NE + e];
    float w = ew[e];
    int p = atomicAdd(&cursor[c], 1);
    int2 pk; pk.x = r; pk.y = __float_as_int(w);
    srt[p] = pk;                       // one 8B scattered store
    float a = __expf(w * INV_TEMP);    // row-side contribution via atomics;
    atomicAdd(&den[r], a);             // col-side comes from the CSR in k_nodeA
    atomicAdd(&num[r], w * a);
}

// ---- node pass over CSR: degf -> dis, col-side den/num -> nw ----
__global__ void k_nodeA(const int* __restrict__ indptr, const int2* __restrict__ srt,
                        const float* __restrict__ den, const float* __restrict__ num,
                        float* __restrict__ dis, float* __restrict__ nw) {
    int i = blockIdx.x * 256 + threadIdx.x;
    if (i >= NN) return;
    int beg = indptr[i], end = indptr[i + 1];
    float sumw = 0.f, dcol = 0.f, ncol = 0.f;
    for (int e = beg; e < end; ++e) {
        float w = __int_as_float(srt[e].y);
        float a = __expf(w * INV_TEMP);
        sumw += w;
        dcol += a;
        ncol += w * a;
    }
    dis[i] = rsqrtf(sumw + 1.0f);      // +1 = self-loop weight
    float D = den[i] + dcol;
    float Nm = num[i] + ncol;
    nw[i] = (D > 0.f) ? Nm / fmaxf(D, 1e-16f) : 0.f;
}

// ---- rewrite payload w -> dis[r]*w (after nodeA, before aggs) ----
__global__ void k_fixnorm(int2* __restrict__ srt, const float* __restrict__ dis) {
    int e = blockIdx.x * 256 + threadIdx.x;
    if (e >= NE) return;
    int2 p = srt[e];
    ((float*)srt)[2 * e + 1] = dis[p.x] * __int_as_float(p.y);
}

// ---- dense GEMM: T[N,64](bf16) = Hin[N,64] @ W[64,64]; 16 rows/block ----
__global__ void k_gemm(const float* __restrict__ Hin, const float* __restrict__ W,
                       bf16* __restrict__ T) {
    __shared__ float Ws[64 * 64];
    __shared__ float Hs[16 * 64];
    int tid = threadIdx.x;
    const float4* W4 = (const float4*)W;
    float4* Ws4 = (float4*)Ws;
#pragma unroll
    for (int i = 0; i < 4; ++i) Ws4[tid + i * 256] = W4[tid + i * 256];
    int row0 = blockIdx.x * 16;   // NN % 16 == 0 -> no guard
    const float4* H4 = (const float4*)(Hin + (size_t)row0 * HD);
    ((float4*)Hs)[tid] = H4[tid];
    __syncthreads();
    int j = tid & 63, rq = tid >> 6;
    float acc[4] = {0.f, 0.f, 0.f, 0.f};
    for (int k = 0; k < 64; ++k) {
        float wv = Ws[k * 64 + j];
#pragma unroll
        for (int rr = 0; rr < 4; ++rr)
            acc[rr] += Hs[(rq * 4 + rr) * 64 + k] * wv;
    }
#pragma unroll
    for (int rr = 0; rr < 4; ++rr)
        T[(row0 + rq * 4 + rr) * HD + j] = __float2bfloat16(acc[rr]);
}

// ---- CSR aggregation: one wave per node, lane = feature; 4x ILP unroll ----
// payload already dis[r]*w; dis[c] factored out of the sum
__global__ void k_agg(const bf16* __restrict__ T, const int* __restrict__ indptr,
                      const int2* __restrict__ srt,
                      const float* __restrict__ dis, const float* __restrict__ bias,
                      float* __restrict__ Hout, int lrelu) {
    int wv = threadIdx.x >> 6, lane = threadIdx.x & 63;
    int node = blockIdx.x * 4 + wv;
    if (node >= NN) return;
    float d = dis[node];
    float self = b2f(T[node * HD + lane]);
    float acc = 0.f;
    int beg = indptr[node], end = indptr[node + 1];
    int e = beg;
    for (; e + 4 <= end; e += 4) {
        int2 p0 = srt[e], p1 = srt[e + 1], p2 = srt[e + 2], p3 = srt[e + 3];
        float v0 = b2f(T[p0.x * HD + lane]);
        float v1 = b2f(T[p1.x * HD + lane]);
        float v2 = b2f(T[p2.x * HD + lane]);
        float v3 = b2f(T[p3.x * HD + lane]);
        acc += __int_as_float(p0.y) * v0;
        acc += __int_as_float(p1.y) * v1;
        acc += __int_as_float(p2.y) * v2;
        acc += __int_as_float(p3.y) * v3;
    }
    for (; e < end; ++e) {
        int2 p = srt[e];
        acc += __int_as_float(p.y) * b2f(T[p.x * HD + lane]);
    }
    float res = bias[lane] + d * (d * self + acc);
    if (lrelu) res = res > 0.f ? res : NEG_SLOPE * res;
    Hout[node * HD + lane] = res;
}

// ---- graph boundaries from sorted batch (no atomics) ----
__global__ void k_gsbound(const int* __restrict__ batch, int* __restrict__ gstart) {
    int n = blockIdx.x * 256 + threadIdx.x;
    if (n >= NN) return;
    int b = batch[n];
    int prev = (n == 0) ? -1 : batch[n - 1];
    if (b != prev) gstart[b] = n;   // batch sorted -> first occurrence, single writer
}

// ---- weighted pooling: one block (4 waves) per graph; suffix-min boundary fix ----
__global__ void k_pool(const float* __restrict__ H3, const float* __restrict__ nw,
                       const int* __restrict__ gstart, float* __restrict__ sfeat,
                       float* __restrict__ out_feats) {
    __shared__ float sred[4][64];
    __shared__ float wred[4];
    __shared__ float wsum_s;
    __shared__ int sbeg, send;
    int b = blockIdx.x;
    if (threadIdx.x == 0) {            // suffix-min fix for empty graphs
        int mn = NN;
        for (int j = NB; j > b; --j) mn = min(mn, gstart[j]);
        send = mn;
        sbeg = min(mn, gstart[b]);
    }
    __syncthreads();
    int wv = threadIdx.x >> 6, lane = threadIdx.x & 63;
    int beg = sbeg, end = send;
    float accs = 0.f, accw = 0.f;
    for (int n = beg + wv; n < end; n += 4) {
        float wn = nw[n];
        accs += wn * H3[n * HD + lane];
        accw += wn;       // identical across lanes of this wave
    }
    sred[wv][lane] = accs;
    if (lane == 0) wred[wv] = accw;
    __syncthreads();
    if (threadIdx.x < 64) {
        float s = sred[0][lane] + sred[1][lane] + sred[2][lane] + sred[3][lane];
        sred[0][lane] = s;
        if (lane == 0) wsum_s = wred[0] + wred[1] + wred[2] + wred[3];
    }
    __syncthreads();
    if (threadIdx.x < 64) {
        float s = sred[0][lane];
        float mean = s / fmaxf(wsum_s, 1e-16f);
        sfeat[b * 128 + lane] = s;
        sfeat[b * 128 + 64 + lane] = mean;
        out_feats[b * 128 + lane] = s;
        out_feats[b * 128 + 64 + lane] = mean;
    }
}

// ---- head MLP + softmax; one block per graph; fp32 out ----
// out layout (fp32 elements): logits[0,1280) probs[1280,2560) feats[2560,18944)
//                             embeds[18944,27136) hout[27136,35328)
__global__ void k_mlp(const float* __restrict__ sfeat, const float* __restrict__ Wlin,
                      const float* __restrict__ blin, const float* __restrict__ Wout,
                      const float* __restrict__ bout, float* __restrict__ out) {
    __shared__ float fs[128];
    __shared__ float hs[64];
    __shared__ float lg[10];
    int b = blockIdx.x, t = threadIdx.x;   // 128 threads
    fs[t] = sfeat[b * 128 + t];
    __syncthreads();
    if (t < 64) {
        float acc = blin[t];
        for (int k = 0; k < 128; ++k) acc += fs[k] * Wlin[k * 64 + t];
        out[18944 + b * 64 + t] = acc;
        float h = fmaxf(acc, 0.f);
        out[27136 + b * 64 + t] = h;
        hs[t] = h;
    }
    __syncthreads();
    if (t < NC) {
        float acc = bout[t];
        for (int j = 0; j < 64; ++j) acc += hs[j] * Wout[j * NC + t];
        lg[t] = acc;
        out[b * NC + t] = acc;
    }
    __syncthreads();
    if (t < NC) {
        float mx = lg[0];
        for (int k = 1; k < NC; ++k) mx = fmaxf(mx, lg[k]);
        float se = 0.f;
        for (int k = 0; k < NC; ++k) se += __expf(lg[k] - mx);
        float p = __expf(lg[t] - mx) / se;
        out[1280 + b * NC + t] = p;
    }
}

extern "C" void kernel_launch(void* const* d_in, const int* in_sizes, int n_in,
                              void* d_out, int out_size, void* d_ws, size_t ws_size,
                              hipStream_t stream) {
    const float* x    = (const float*)d_in[0];
    const int*   ei   = (const int*)  d_in[1];
    const float* ew   = (const float*)d_in[2];
    const int*   batch= (const int*)  d_in[3];
    const float* W1   = (const float*)d_in[4];
    const float* b1   = (const float*)d_in[5];
    const float* W2   = (const float*)d_in[6];
    const float* b2   = (const float*)d_in[7];
    const float* W3   = (const float*)d_in[8];
    const float* b3   = (const float*)d_in[9];
    const float* Wlin = (const float*)d_in[10];
    const float* blin = (const float*)d_in[11];
    const float* Wout = (const float*)d_in[12];
    const float* bout = (const float*)d_in[13];
    float* out = (float*)d_out;

    char* ws = (char*)d_ws;
    size_t off = 0;
    auto alloc = [&](size_t bytes) -> void* {
        void* p = ws + off;
        off = (off + bytes + 255) & ~(size_t)255;
        return p;
    };
    // zeroed group (one contiguous memset): cnt, den, num
    int*   cnt  = (int*)  alloc(NN * 4);
    float* den  = (float*)alloc(NN * 4);
    float* num  = (float*)alloc(NN * 4);
    size_t zbytes = off;
    // rest (fully overwritten each call)
    float* dis    = (float*)alloc(NN * 4);
    int* indptr   = (int*)  alloc((NN + 1) * 4);
    int* cursor   = (int*)  alloc(NN * 4);
    float* nw     = (float*)alloc(NN * 4);
    int* bsum     = (int*)  alloc(512 * 4);
    int2* srt     = (int2*) alloc((size_t)NE * 8);
    bf16* Tbuf    = (bf16*) alloc((size_t)NN * HD * 2);
    float* Hbuf   = (float*)alloc((size_t)NN * HD * 4);
    float* sfeat  = (float*)alloc(NB * 128 * 4);
    int* gstart   = (int*)  alloc((NB + 1) * 4);
    (void)ws_size; (void)in_sizes; (void)n_in; (void)out_size;

    const int EB = (NE + 255) / 256;   // 3907
    const int VB = (NN + 255) / 256;   // 391

    hipMemsetAsync(ws, 0, zbytes, stream);
    k_edge1<<<EB, 256, 0, stream>>>(ei, cnt);
    k_scan1<<<VB, 256, 0, stream>>>(cnt, bsum);
    k_scan2<<<1, 512, 0, stream>>>(bsum, VB, gstart);
    k_scan3<<<VB, 256, 0, stream>>>(cnt, bsum, indptr, cursor);
    k_edge2<<<EB, 256, 0, stream>>>(ei, ew, cursor, srt, den, num);
    k_nodeA<<<VB, 256, 0, stream>>>(indptr, srt, den, num, dis, nw);
    k_fixnorm<<<EB, 256, 0, stream>>>(srt, dis);
    k_gsbound<<<VB, 256, 0, stream>>>(batch, gstart);

    // layer 1: x -> Tbuf -> agg -> Hbuf (leaky relu)
    k_gemm<<<NN / 16, 256, 0, stream>>>(x, W1, Tbuf);
    k_agg<<<NN / 4, 256, 0, stream>>>(Tbuf, indptr, srt, dis, b1, Hbuf, 1);
    // layer 2
    k_gemm<<<NN / 16, 256, 0, stream>>>(Hbuf, W2, Tbuf);
    k_agg<<<NN / 4, 256, 0, stream>>>(Tbuf, indptr, srt, dis, b2, Hbuf, 1);
    // layer 3 (no activation)
    k_gemm<<<NN / 16, 256, 0, stream>>>(Hbuf, W3, Tbuf);
    k_agg<<<NN / 4, 256, 0, stream>>>(Tbuf, indptr, srt, dis, b3, Hbuf, 0);

    // pooling + head
    k_pool<<<NB, 256, 0, stream>>>(Hbuf, nw, gstart, sfeat, out + 2560);
    k_mlp<<<NB, 128, 0, stream>>>(sfeat, Wlin, blin, Wout, bout, out);
}